// Round 1
// baseline (12255.949 us; speedup 1.0000x reference)
//
#include <hip/hip_runtime.h>
#include <math.h>

#define DD 512
#define G3 1536
#define BM 64
#define BN 64
#define BK 16

__device__ __forceinline__ float sigm(float x) { return 1.0f / (1.0f + expf(-x)); }

// Precompute gi[t][j] = (w_ih @ emb[t])[j] + b_ih[j] for both nets.
__global__ void msd_gi_kernel(const float* __restrict__ emb,
                              const float* __restrict__ wf, const float* __restrict__ bf,
                              const float* __restrict__ ws_, const float* __restrict__ bs,
                              float* __restrict__ gif, float* __restrict__ gis)
{
    int t = blockIdx.x;
    int part = blockIdx.y;          // 0..11
    int net = part / 6;             // 0 fast, 1 slow
    int j = (part % 6) * 256 + threadIdx.x;
    __shared__ float e[DD];
    for (int k = threadIdx.x; k < DD; k += 256) e[k] = emb[t * DD + k];
    __syncthreads();
    const float* w = net ? ws_ : wf;
    const float* b = net ? bs : bf;
    const float* wr = w + (size_t)j * DD;
    float acc = b[j];
    #pragma unroll 8
    for (int k = 0; k < DD; k += 4) {
        float4 wv = *reinterpret_cast<const float4*>(wr + k);
        acc = fmaf(wv.x, e[k], acc);
        acc = fmaf(wv.y, e[k + 1], acc);
        acc = fmaf(wv.z, e[k + 2], acc);
        acc = fmaf(wv.w, e[k + 3], acc);
    }
    (net ? gis : gif)[t * G3 + j] = acc;
}

__global__ void msd_init_kernel(const float* __restrict__ z, float* __restrict__ a,
                                float* __restrict__ b, int n)
{
    int i = blockIdx.x * blockDim.x + threadIdx.x;
    if (i < n) { float v = z[i]; a[i] = v; b[i] = v; }
}

// One GRU step: h_new = GRUCell(emb_t, h). Computes the 3 gate dot products
// (K=512) for a 64x64 output tile, then applies the gate nonlinearity.
// blockIdx.z == 0 -> fast net, == 1 -> slow net (only launched on update steps).
__global__ __launch_bounds__(256) void msd_gru_kernel(
    const float* __restrict__ hf, const float* __restrict__ hs,
    const float* __restrict__ wF, const float* __restrict__ wS,
    const float* __restrict__ bhhF, const float* __restrict__ bhhS,
    const float* __restrict__ giF, const float* __restrict__ giS,
    float* __restrict__ hfn, float* __restrict__ hsn)
{
    const int slow = blockIdx.z;
    const float* h   = slow ? hs : hf;
    const float* w   = slow ? wS : wF;
    const float* bhh = slow ? bhhS : bhhF;
    const float* gi  = slow ? giS : giF;
    float* hn        = slow ? hsn : hfn;

    const int row0 = blockIdx.y * BM;
    const int col0 = blockIdx.x * BN;
    const int tid = threadIdx.x;
    const int tx = tid & 15, ty = tid >> 4;
    const int lr = tid >> 2;           // 0..63
    const int lk = (tid & 3) << 2;     // 0,4,8,12

    __shared__ float As[BM][BK + 1];
    __shared__ float Ws[3][BN][BK + 1];

    float acc[3][4][4];
    #pragma unroll
    for (int g = 0; g < 3; ++g)
        #pragma unroll
        for (int m = 0; m < 4; ++m)
            #pragma unroll
            for (int n = 0; n < 4; ++n) acc[g][m][n] = 0.f;

    const float* pa  = h + (size_t)(row0 + lr) * DD + lk;
    const float* pw0 = w + (size_t)(col0 + lr) * DD + lk;
    const float* pw1 = pw0 + (size_t)512 * DD;
    const float* pw2 = pw1 + (size_t)512 * DD;

    float4 ra = *reinterpret_cast<const float4*>(pa);
    float4 r0 = *reinterpret_cast<const float4*>(pw0);
    float4 r1 = *reinterpret_cast<const float4*>(pw1);
    float4 r2 = *reinterpret_cast<const float4*>(pw2);

    for (int kt = 0; kt < DD / BK; ++kt) {
        As[lr][lk] = ra.x; As[lr][lk + 1] = ra.y; As[lr][lk + 2] = ra.z; As[lr][lk + 3] = ra.w;
        Ws[0][lr][lk] = r0.x; Ws[0][lr][lk + 1] = r0.y; Ws[0][lr][lk + 2] = r0.z; Ws[0][lr][lk + 3] = r0.w;
        Ws[1][lr][lk] = r1.x; Ws[1][lr][lk + 1] = r1.y; Ws[1][lr][lk + 2] = r1.z; Ws[1][lr][lk + 3] = r1.w;
        Ws[2][lr][lk] = r2.x; Ws[2][lr][lk + 1] = r2.y; Ws[2][lr][lk + 2] = r2.z; Ws[2][lr][lk + 3] = r2.w;
        __syncthreads();
        if (kt + 1 < DD / BK) {
            int k0 = (kt + 1) * BK;
            ra = *reinterpret_cast<const float4*>(pa + k0);
            r0 = *reinterpret_cast<const float4*>(pw0 + k0);
            r1 = *reinterpret_cast<const float4*>(pw1 + k0);
            r2 = *reinterpret_cast<const float4*>(pw2 + k0);
        }
        #pragma unroll
        for (int k = 0; k < BK; ++k) {
            float a[4];
            #pragma unroll
            for (int m = 0; m < 4; ++m) a[m] = As[ty * 4 + m][k];
            #pragma unroll
            for (int g = 0; g < 3; ++g) {
                float wv[4];
                #pragma unroll
                for (int n = 0; n < 4; ++n) wv[n] = Ws[g][tx * 4 + n][k];
                #pragma unroll
                for (int m = 0; m < 4; ++m)
                    #pragma unroll
                    for (int n = 0; n < 4; ++n)
                        acc[g][m][n] = fmaf(a[m], wv[n], acc[g][m][n]);
            }
        }
        __syncthreads();
    }

    #pragma unroll
    for (int m = 0; m < 4; ++m) {
        int row = row0 + ty * 4 + m;
        #pragma unroll
        for (int n = 0; n < 4; ++n) {
            int col = col0 + tx * 4 + n;
            float r  = sigm(gi[col]        + bhh[col]        + acc[0][m][n]);
            float zg = sigm(gi[col + 512]  + bhh[col + 512]  + acc[1][m][n]);
            float nn = tanhf(gi[col + 1024] + r * (acc[2][m][n] + bhh[col + 1024]));
            float hv = h[(size_t)row * DD + col];
            hn[(size_t)row * DD + col] = (1.f - zg) * nn + zg * hv;
        }
    }
}

// Gate logits: glog = concat(zfn, zs) @ gate_w.T + gate_b   (K = 1024)
__global__ __launch_bounds__(256) void msd_gate_kernel(
    const float* __restrict__ zfn, const float* __restrict__ zs,
    const float* __restrict__ gw, const float* __restrict__ gb,
    float* __restrict__ glog)
{
    const int row0 = blockIdx.y * BM;
    const int col0 = blockIdx.x * BN;
    const int tid = threadIdx.x;
    const int tx = tid & 15, ty = tid >> 4;
    const int lr = tid >> 2;
    const int lk = (tid & 3) << 2;

    __shared__ float As[BM][BK + 1];
    __shared__ float Ws[BN][BK + 1];

    float acc[4][4];
    #pragma unroll
    for (int m = 0; m < 4; ++m)
        #pragma unroll
        for (int n = 0; n < 4; ++n) acc[m][n] = 0.f;

    const float* gwr = gw + (size_t)(col0 + lr) * 1024 + lk;

    // A load helper: K in [0,512) from zfn, [512,1024) from zs
    int k0 = 0;
    float4 ra = *reinterpret_cast<const float4*>(zfn + (size_t)(row0 + lr) * DD + lk);
    float4 rw = *reinterpret_cast<const float4*>(gwr);

    for (int kt = 0; kt < 1024 / BK; ++kt) {
        As[lr][lk] = ra.x; As[lr][lk + 1] = ra.y; As[lr][lk + 2] = ra.z; As[lr][lk + 3] = ra.w;
        Ws[lr][lk] = rw.x; Ws[lr][lk + 1] = rw.y; Ws[lr][lk + 2] = rw.z; Ws[lr][lk + 3] = rw.w;
        __syncthreads();
        if (kt + 1 < 1024 / BK) {
            k0 = (kt + 1) * BK;
            if (k0 < 512)
                ra = *reinterpret_cast<const float4*>(zfn + (size_t)(row0 + lr) * DD + k0 + lk);
            else
                ra = *reinterpret_cast<const float4*>(zs + (size_t)(row0 + lr) * DD + (k0 - 512) + lk);
            rw = *reinterpret_cast<const float4*>(gwr + k0);
        }
        #pragma unroll
        for (int k = 0; k < BK; ++k) {
            float a[4], wv[4];
            #pragma unroll
            for (int m = 0; m < 4; ++m) a[m] = As[ty * 4 + m][k];
            #pragma unroll
            for (int n = 0; n < 4; ++n) wv[n] = Ws[tx * 4 + n][k];
            #pragma unroll
            for (int m = 0; m < 4; ++m)
                #pragma unroll
                for (int n = 0; n < 4; ++n)
                    acc[m][n] = fmaf(a[m], wv[n], acc[m][n]);
        }
        __syncthreads();
    }

    #pragma unroll
    for (int m = 0; m < 4; ++m) {
        int row = row0 + ty * 4 + m;
        #pragma unroll
        for (int n = 0; n < 4; ++n) {
            int col = col0 + tx * 4 + n;
            glog[(size_t)row * DD + col] = acc[m][n] + gb[col];
        }
    }
}

// Fuse: g = sigmoid(glog); pre = g*zfn + (1-g)*zs + zf_old; out = LN(pre).
// One block (128 threads) per batch row; also writes the new z_fast carry.
__global__ __launch_bounds__(128) void msd_fuse_ln_kernel(
    const float* __restrict__ glog, const float* __restrict__ zfn,
    const float* __restrict__ zs, const float* __restrict__ zfold,
    const float* __restrict__ gamma, const float* __restrict__ beta,
    float* __restrict__ outt, float* __restrict__ zfnext, int TD)
{
    int b = blockIdx.x;
    int j = threadIdx.x * 4;
    size_t base = (size_t)b * DD + j;
    float4 gl = *reinterpret_cast<const float4*>(glog + base);
    float4 fa = *reinterpret_cast<const float4*>(zfn + base);
    float4 sa = *reinterpret_cast<const float4*>(zs + base);
    float4 fo = *reinterpret_cast<const float4*>(zfold + base);

    float p[4];
    {
        float g0 = sigm(gl.x); p[0] = g0 * fa.x + (1.f - g0) * sa.x + fo.x;
        float g1 = sigm(gl.y); p[1] = g1 * fa.y + (1.f - g1) * sa.y + fo.y;
        float g2 = sigm(gl.z); p[2] = g2 * fa.z + (1.f - g2) * sa.z + fo.z;
        float g3 = sigm(gl.w); p[3] = g3 * fa.w + (1.f - g3) * sa.w + fo.w;
    }
    float s  = p[0] + p[1] + p[2] + p[3];
    float s2 = p[0] * p[0] + p[1] * p[1] + p[2] * p[2] + p[3] * p[3];
    #pragma unroll
    for (int off = 32; off > 0; off >>= 1) {
        s  += __shfl_down(s, off);
        s2 += __shfl_down(s2, off);
    }
    __shared__ float red[4];
    if ((threadIdx.x & 63) == 0) { int wv = threadIdx.x >> 6; red[wv] = s; red[2 + wv] = s2; }
    __syncthreads();
    float S  = red[0] + red[1];
    float S2 = red[2] + red[3];
    float mu  = S * (1.0f / DD);
    float var = S2 * (1.0f / DD) - mu * mu;
    float inv = rsqrtf(var + 1e-5f);
    float4 gm = *reinterpret_cast<const float4*>(gamma + j);
    float4 bt = *reinterpret_cast<const float4*>(beta + j);
    float4 o;
    o.x = (p[0] - mu) * inv * gm.x + bt.x;
    o.y = (p[1] - mu) * inv * gm.y + bt.y;
    o.z = (p[2] - mu) * inv * gm.z + bt.z;
    o.w = (p[3] - mu) * inv * gm.w + bt.w;
    *reinterpret_cast<float4*>(outt + (size_t)b * TD + j) = o;
    *reinterpret_cast<float4*>(zfnext + base) = o;
}

extern "C" void kernel_launch(void* const* d_in, const int* in_sizes, int n_in,
                              void* d_out, int out_size, void* d_ws, size_t ws_size,
                              hipStream_t stream)
{
    const float* z_init = (const float*)d_in[0];
    const float* emb    = (const float*)d_in[1];
    const float* f_wih  = (const float*)d_in[2];
    const float* f_whh  = (const float*)d_in[3];
    const float* f_bih  = (const float*)d_in[4];
    const float* f_bhh  = (const float*)d_in[5];
    const float* s_wih  = (const float*)d_in[6];
    const float* s_whh  = (const float*)d_in[7];
    const float* s_bih  = (const float*)d_in[8];
    const float* s_bhh  = (const float*)d_in[9];
    const float* gw     = (const float*)d_in[10];
    const float* gb     = (const float*)d_in[11];
    const float* gamma  = (const float*)d_in[12];
    const float* beta   = (const float*)d_in[13];

    const int B = in_sizes[0] / DD;          // 2048
    const int T = out_size / in_sizes[0];    // 64 (num_steps; avoid device read)
    float* out = (float*)d_out;

    char* p = (char*)d_ws;
    float* gi_f = (float*)p; p += (size_t)T * G3 * sizeof(float);
    float* gi_s = (float*)p; p += (size_t)T * G3 * sizeof(float);
    size_t bd = (size_t)B * DD * sizeof(float);
    float* zf0  = (float*)p; p += bd;
    float* zf1  = (float*)p; p += bd;
    float* zs0  = (float*)p; p += bd;
    float* zs1  = (float*)p; p += bd;
    float* zfn  = (float*)p; p += bd;
    float* glog = (float*)p; p += bd;

    msd_gi_kernel<<<dim3(T, 12), 256, 0, stream>>>(emb, f_wih, f_bih, s_wih, s_bih, gi_f, gi_s);
    msd_init_kernel<<<(B * DD + 255) / 256, 256, 0, stream>>>(z_init, zf0, zs0, B * DD);

    float* zfc[2] = {zf0, zf1};
    float* zsc[2] = {zs0, zs1};
    int fc = 0, sc = 0;
    for (int t = 0; t < T; ++t) {
        int upd = (t % 2 == 0) ? 1 : 0;
        dim3 grid(DD / BN, B / BM, upd ? 2 : 1);
        msd_gru_kernel<<<grid, 256, 0, stream>>>(zfc[fc], zsc[sc], f_whh, s_whh, f_bhh, s_bhh,
            gi_f + (size_t)t * G3, gi_s + (size_t)t * G3, zfn, zsc[sc ^ 1]);
        if (upd) sc ^= 1;
        msd_gate_kernel<<<dim3(DD / BN, B / BM), 256, 0, stream>>>(zfn, zsc[sc], gw, gb, glog);
        msd_fuse_ln_kernel<<<B, 128, 0, stream>>>(glog, zfn, zsc[sc], zfc[fc], gamma, beta,
            out + (size_t)t * DD, zfc[fc ^ 1], T * DD);
        fc ^= 1;
    }
}

// Round 2
// 12247.226 us; speedup vs baseline: 1.0007x; 1.0007x over previous
//
#include <hip/hip_runtime.h>
#include <math.h>

#define DD 512
#define G3 1536
#define BM 64
#define BN 64
#define BK 16

__device__ __forceinline__ float sigm(float x) { return 1.0f / (1.0f + expf(-x)); }

// Precompute gi[t][j] = (w_ih @ emb[t])[j] + b_ih[j] for both nets.
__global__ void msd_gi_kernel(const float* __restrict__ emb,
                              const float* __restrict__ wf, const float* __restrict__ bf,
                              const float* __restrict__ ws_, const float* __restrict__ bs,
                              float* __restrict__ gif, float* __restrict__ gis)
{
    int t = blockIdx.x;
    int part = blockIdx.y;          // 0..11
    int net = part / 6;             // 0 fast, 1 slow
    int j = (part % 6) * 256 + threadIdx.x;
    __shared__ float e[DD];
    for (int k = threadIdx.x; k < DD; k += 256) e[k] = emb[t * DD + k];
    __syncthreads();
    const float* w = net ? ws_ : wf;
    const float* b = net ? bs : bf;
    const float* wr = w + (size_t)j * DD;
    float acc = b[j];
    #pragma unroll 8
    for (int k = 0; k < DD; k += 4) {
        float4 wv = *reinterpret_cast<const float4*>(wr + k);
        acc = fmaf(wv.x, e[k], acc);
        acc = fmaf(wv.y, e[k + 1], acc);
        acc = fmaf(wv.z, e[k + 2], acc);
        acc = fmaf(wv.w, e[k + 3], acc);
    }
    (net ? gis : gif)[t * G3 + j] = acc;
}

__global__ void msd_init_kernel(const float* __restrict__ z, float* __restrict__ a,
                                float* __restrict__ b, int n)
{
    int i = blockIdx.x * blockDim.x + threadIdx.x;
    if (i < n) { float v = z[i]; a[i] = v; b[i] = v; }
}

// One GRU step: h_new = GRUCell(emb_t, h). Computes the 3 gate dot products
// (K=512) for a 64x64 output tile, then applies the gate nonlinearity.
// blockIdx.z == 0 -> fast net, == 1 -> slow net (only launched on update steps).
__global__ __launch_bounds__(256) void msd_gru_kernel(
    const float* __restrict__ hf, const float* __restrict__ hs,
    const float* __restrict__ wF, const float* __restrict__ wS,
    const float* __restrict__ bhhF, const float* __restrict__ bhhS,
    const float* __restrict__ giF, const float* __restrict__ giS,
    float* __restrict__ hfn, float* __restrict__ hsn)
{
    const int slow = blockIdx.z;
    const float* h   = slow ? hs : hf;
    const float* w   = slow ? wS : wF;
    const float* bhh = slow ? bhhS : bhhF;
    const float* gi  = slow ? giS : giF;
    float* hn        = slow ? hsn : hfn;

    const int row0 = blockIdx.y * BM;
    const int col0 = blockIdx.x * BN;
    const int tid = threadIdx.x;
    const int tx = tid & 15, ty = tid >> 4;
    const int lr = tid >> 2;           // 0..63
    const int lk = (tid & 3) << 2;     // 0,4,8,12

    __shared__ float As[BM][BK + 1];
    __shared__ float Ws[3][BN][BK + 1];

    float acc[3][4][4];
    #pragma unroll
    for (int g = 0; g < 3; ++g)
        #pragma unroll
        for (int m = 0; m < 4; ++m)
            #pragma unroll
            for (int n = 0; n < 4; ++n) acc[g][m][n] = 0.f;

    const float* pa  = h + (size_t)(row0 + lr) * DD + lk;
    const float* pw0 = w + (size_t)(col0 + lr) * DD + lk;
    const float* pw1 = pw0 + (size_t)512 * DD;
    const float* pw2 = pw1 + (size_t)512 * DD;

    float4 ra = *reinterpret_cast<const float4*>(pa);
    float4 r0 = *reinterpret_cast<const float4*>(pw0);
    float4 r1 = *reinterpret_cast<const float4*>(pw1);
    float4 r2 = *reinterpret_cast<const float4*>(pw2);

    for (int kt = 0; kt < DD / BK; ++kt) {
        As[lr][lk] = ra.x; As[lr][lk + 1] = ra.y; As[lr][lk + 2] = ra.z; As[lr][lk + 3] = ra.w;
        Ws[0][lr][lk] = r0.x; Ws[0][lr][lk + 1] = r0.y; Ws[0][lr][lk + 2] = r0.z; Ws[0][lr][lk + 3] = r0.w;
        Ws[1][lr][lk] = r1.x; Ws[1][lr][lk + 1] = r1.y; Ws[1][lr][lk + 2] = r1.z; Ws[1][lr][lk + 3] = r1.w;
        Ws[2][lr][lk] = r2.x; Ws[2][lr][lk + 1] = r2.y; Ws[2][lr][lk + 2] = r2.z; Ws[2][lr][lk + 3] = r2.w;
        __syncthreads();
        if (kt + 1 < DD / BK) {
            int k0 = (kt + 1) * BK;
            ra = *reinterpret_cast<const float4*>(pa + k0);
            r0 = *reinterpret_cast<const float4*>(pw0 + k0);
            r1 = *reinterpret_cast<const float4*>(pw1 + k0);
            r2 = *reinterpret_cast<const float4*>(pw2 + k0);
        }
        #pragma unroll
        for (int k = 0; k < BK; ++k) {
            float a[4];
            #pragma unroll
            for (int m = 0; m < 4; ++m) a[m] = As[ty * 4 + m][k];
            #pragma unroll
            for (int g = 0; g < 3; ++g) {
                float wv[4];
                #pragma unroll
                for (int n = 0; n < 4; ++n) wv[n] = Ws[g][tx * 4 + n][k];
                #pragma unroll
                for (int m = 0; m < 4; ++m)
                    #pragma unroll
                    for (int n = 0; n < 4; ++n)
                        acc[g][m][n] = fmaf(a[m], wv[n], acc[g][m][n]);
            }
        }
        __syncthreads();
    }

    #pragma unroll
    for (int m = 0; m < 4; ++m) {
        int row = row0 + ty * 4 + m;
        #pragma unroll
        for (int n = 0; n < 4; ++n) {
            int col = col0 + tx * 4 + n;
            float r  = sigm(gi[col]        + bhh[col]        + acc[0][m][n]);
            float zg = sigm(gi[col + 512]  + bhh[col + 512]  + acc[1][m][n]);
            float nn = tanhf(gi[col + 1024] + r * (acc[2][m][n] + bhh[col + 1024]));
            float hv = h[(size_t)row * DD + col];
            hn[(size_t)row * DD + col] = (1.f - zg) * nn + zg * hv;
        }
    }
}

// Gate logits: glog = concat(zfn, zs) @ gate_w.T + gate_b   (K = 1024)
__global__ __launch_bounds__(256) void msd_gate_kernel(
    const float* __restrict__ zfn, const float* __restrict__ zs,
    const float* __restrict__ gw, const float* __restrict__ gb,
    float* __restrict__ glog)
{
    const int row0 = blockIdx.y * BM;
    const int col0 = blockIdx.x * BN;
    const int tid = threadIdx.x;
    const int tx = tid & 15, ty = tid >> 4;
    const int lr = tid >> 2;
    const int lk = (tid & 3) << 2;

    __shared__ float As[BM][BK + 1];
    __shared__ float Ws[BN][BK + 1];

    float acc[4][4];
    #pragma unroll
    for (int m = 0; m < 4; ++m)
        #pragma unroll
        for (int n = 0; n < 4; ++n) acc[m][n] = 0.f;

    const float* gwr = gw + (size_t)(col0 + lr) * 1024 + lk;

    // A load helper: K in [0,512) from zfn, [512,1024) from zs
    int k0 = 0;
    float4 ra = *reinterpret_cast<const float4*>(zfn + (size_t)(row0 + lr) * DD + lk);
    float4 rw = *reinterpret_cast<const float4*>(gwr);

    for (int kt = 0; kt < 1024 / BK; ++kt) {
        As[lr][lk] = ra.x; As[lr][lk + 1] = ra.y; As[lr][lk + 2] = ra.z; As[lr][lk + 3] = ra.w;
        Ws[lr][lk] = rw.x; Ws[lr][lk + 1] = rw.y; Ws[lr][lk + 2] = rw.z; Ws[lr][lk + 3] = rw.w;
        __syncthreads();
        if (kt + 1 < 1024 / BK) {
            k0 = (kt + 1) * BK;
            if (k0 < 512)
                ra = *reinterpret_cast<const float4*>(zfn + (size_t)(row0 + lr) * DD + k0 + lk);
            else
                ra = *reinterpret_cast<const float4*>(zs + (size_t)(row0 + lr) * DD + (k0 - 512) + lk);
            rw = *reinterpret_cast<const float4*>(gwr + k0);
        }
        #pragma unroll
        for (int k = 0; k < BK; ++k) {
            float a[4], wv[4];
            #pragma unroll
            for (int m = 0; m < 4; ++m) a[m] = As[ty * 4 + m][k];
            #pragma unroll
            for (int n = 0; n < 4; ++n) wv[n] = Ws[tx * 4 + n][k];
            #pragma unroll
            for (int m = 0; m < 4; ++m)
                #pragma unroll
                for (int n = 0; n < 4; ++n)
                    acc[m][n] = fmaf(a[m], wv[n], acc[m][n]);
        }
        __syncthreads();
    }

    #pragma unroll
    for (int m = 0; m < 4; ++m) {
        int row = row0 + ty * 4 + m;
        #pragma unroll
        for (int n = 0; n < 4; ++n) {
            int col = col0 + tx * 4 + n;
            glog[(size_t)row * DD + col] = acc[m][n] + gb[col];
        }
    }
}

// Fuse: g = sigmoid(glog); pre = g*zfn + (1-g)*zs + zf_old; out = LN(pre).
// One block (128 threads) per batch row; also writes the new z_fast carry.
__global__ __launch_bounds__(128) void msd_fuse_ln_kernel(
    const float* __restrict__ glog, const float* __restrict__ zfn,
    const float* __restrict__ zs, const float* __restrict__ zfold,
    const float* __restrict__ gamma, const float* __restrict__ beta,
    float* __restrict__ outt, float* __restrict__ zfnext, int TD)
{
    int b = blockIdx.x;
    int j = threadIdx.x * 4;
    size_t base = (size_t)b * DD + j;
    float4 gl = *reinterpret_cast<const float4*>(glog + base);
    float4 fa = *reinterpret_cast<const float4*>(zfn + base);
    float4 sa = *reinterpret_cast<const float4*>(zs + base);
    float4 fo = *reinterpret_cast<const float4*>(zfold + base);

    float p[4];
    {
        float g0 = sigm(gl.x); p[0] = g0 * fa.x + (1.f - g0) * sa.x + fo.x;
        float g1 = sigm(gl.y); p[1] = g1 * fa.y + (1.f - g1) * sa.y + fo.y;
        float g2 = sigm(gl.z); p[2] = g2 * fa.z + (1.f - g2) * sa.z + fo.z;
        float g3 = sigm(gl.w); p[3] = g3 * fa.w + (1.f - g3) * sa.w + fo.w;
    }
    float s  = p[0] + p[1] + p[2] + p[3];
    float s2 = p[0] * p[0] + p[1] * p[1] + p[2] * p[2] + p[3] * p[3];
    #pragma unroll
    for (int off = 32; off > 0; off >>= 1) {
        s  += __shfl_down(s, off);
        s2 += __shfl_down(s2, off);
    }
    __shared__ float red[4];
    if ((threadIdx.x & 63) == 0) { int wv = threadIdx.x >> 6; red[wv] = s; red[2 + wv] = s2; }
    __syncthreads();
    float S  = red[0] + red[1];
    float S2 = red[2] + red[3];
    float mu  = S * (1.0f / DD);
    float var = S2 * (1.0f / DD) - mu * mu;
    float inv = rsqrtf(var + 1e-5f);
    float4 gm = *reinterpret_cast<const float4*>(gamma + j);
    float4 bt = *reinterpret_cast<const float4*>(beta + j);
    float4 o;
    o.x = (p[0] - mu) * inv * gm.x + bt.x;
    o.y = (p[1] - mu) * inv * gm.y + bt.y;
    o.z = (p[2] - mu) * inv * gm.z + bt.z;
    o.w = (p[3] - mu) * inv * gm.w + bt.w;
    *reinterpret_cast<float4*>(outt + (size_t)b * TD + j) = o;
    *reinterpret_cast<float4*>(zfnext + base) = o;
}

extern "C" void kernel_launch(void* const* d_in, const int* in_sizes, int n_in,
                              void* d_out, int out_size, void* d_ws, size_t ws_size,
                              hipStream_t stream)
{
    const float* z_init = (const float*)d_in[0];
    const float* emb    = (const float*)d_in[1];
    const float* f_wih  = (const float*)d_in[2];
    const float* f_whh  = (const float*)d_in[3];
    const float* f_bih  = (const float*)d_in[4];
    const float* f_bhh  = (const float*)d_in[5];
    const float* s_wih  = (const float*)d_in[6];
    const float* s_whh  = (const float*)d_in[7];
    const float* s_bih  = (const float*)d_in[8];
    const float* s_bhh  = (const float*)d_in[9];
    const float* gw     = (const float*)d_in[10];
    const float* gb     = (const float*)d_in[11];
    const float* gamma  = (const float*)d_in[12];
    const float* beta   = (const float*)d_in[13];

    const int B = in_sizes[0] / DD;          // 2048
    const int T = out_size / in_sizes[0];    // 64 (num_steps; avoid device read)
    float* out = (float*)d_out;

    char* p = (char*)d_ws;
    float* gi_f = (float*)p; p += (size_t)T * G3 * sizeof(float);
    float* gi_s = (float*)p; p += (size_t)T * G3 * sizeof(float);
    size_t bd = (size_t)B * DD * sizeof(float);
    float* zf0  = (float*)p; p += bd;
    float* zf1  = (float*)p; p += bd;
    float* zs0  = (float*)p; p += bd;
    float* zs1  = (float*)p; p += bd;
    float* zfn  = (float*)p; p += bd;
    float* glog = (float*)p; p += bd;

    msd_gi_kernel<<<dim3(T, 12), 256, 0, stream>>>(emb, f_wih, f_bih, s_wih, s_bih, gi_f, gi_s);
    msd_init_kernel<<<(B * DD + 255) / 256, 256, 0, stream>>>(z_init, zf0, zs0, B * DD);

    float* zfc[2] = {zf0, zf1};
    float* zsc[2] = {zs0, zs1};
    int fc = 0, sc = 0;
    for (int t = 0; t < T; ++t) {
        int upd = (t % 2 == 0) ? 1 : 0;
        dim3 grid(DD / BN, B / BM, upd ? 2 : 1);
        msd_gru_kernel<<<grid, 256, 0, stream>>>(zfc[fc], zsc[sc], f_whh, s_whh, f_bhh, s_bhh,
            gi_f + (size_t)t * G3, gi_s + (size_t)t * G3, zfn, zsc[sc ^ 1]);
        if (upd) sc ^= 1;
        msd_gate_kernel<<<dim3(DD / BN, B / BM), 256, 0, stream>>>(zfn, zsc[sc], gw, gb, glog);
        msd_fuse_ln_kernel<<<B, 128, 0, stream>>>(glog, zfn, zsc[sc], zfc[fc], gamma, beta,
            out + (size_t)t * DD, zfc[fc ^ 1], T * DD);
        fc ^= 1;
    }
}

// Round 4
// 3348.651 us; speedup vs baseline: 3.6600x; 3.6574x over previous
//
#include <hip/hip_runtime.h>
#include <math.h>

#define DD 512
#define G3 1536

typedef _Float16 half8v __attribute__((ext_vector_type(8)));
typedef __attribute__((ext_vector_type(4))) float f32x4;

__device__ __forceinline__ float sigm(float x) { return 1.0f / (1.0f + expf(-x)); }

// Precompute gi[t][j] = (w_ih @ emb[t])[j] + b_ih[j] for both nets (fp32, tiny).
__global__ void msd_gi_kernel(const float* __restrict__ emb,
                              const float* __restrict__ wf, const float* __restrict__ bf,
                              const float* __restrict__ ws_, const float* __restrict__ bs,
                              float* __restrict__ gif, float* __restrict__ gis)
{
    int t = blockIdx.x;
    int part = blockIdx.y;          // 0..11
    int net = part / 6;             // 0 fast, 1 slow
    int j = (part % 6) * 256 + threadIdx.x;
    __shared__ float e[DD];
    for (int k = threadIdx.x; k < DD; k += 256) e[k] = emb[t * DD + k];
    __syncthreads();
    const float* w = net ? ws_ : wf;
    const float* b = net ? bs : bf;
    const float* wr = w + (size_t)j * DD;
    float acc = b[j];
    #pragma unroll 8
    for (int k = 0; k < DD; k += 4) {
        float4 wv = *reinterpret_cast<const float4*>(wr + k);
        acc = fmaf(wv.x, e[k], acc);
        acc = fmaf(wv.y, e[k + 1], acc);
        acc = fmaf(wv.z, e[k + 2], acc);
        acc = fmaf(wv.w, e[k + 3], acc);
    }
    (net ? gis : gif)[t * G3 + j] = acc;
}

// Convert fp32 array to fp16 (vectorized x4).
__global__ void msd_f2h_kernel(const float* __restrict__ in, _Float16* __restrict__ out, int n4)
{
    int i = blockIdx.x * 256 + threadIdx.x;
    if (i >= n4) return;
    float4 v = reinterpret_cast<const float4*>(in)[i];
    _Float16 o[4] = {(_Float16)v.x, (_Float16)v.y, (_Float16)v.z, (_Float16)v.w};
    *reinterpret_cast<ushort4*>(out + (size_t)i * 4) = *reinterpret_cast<ushort4*>(o);
}

__global__ void msd_init_kernel(const float* __restrict__ z, float* __restrict__ zf32,
                                float* __restrict__ zs32, _Float16* __restrict__ zfh,
                                _Float16* __restrict__ zsh, int n)
{
    int i = blockIdx.x * 256 + threadIdx.x;
    if (i < n) {
        float v = z[i];
        zf32[i] = v; zs32[i] = v;
        _Float16 h = (_Float16)v;
        zfh[i] = h; zsh[i] = h;
    }
}

// GRU step via MFMA (fp16 operands, fp32 accum). Block tile 64x64(x3 gates),
// 4 waves (2x2), wave tile 32x32x3. Operands straight from global (L2-resident),
// 16B/lane contiguous in the verified B^T fragment layout.
// blockIdx.z: 0 = fast net, 1 = slow net (launched only on update steps).
__global__ __launch_bounds__(256) void msd_gru_mfma(
    const _Float16* __restrict__ zfh, const _Float16* __restrict__ zsh,
    const float* __restrict__ zf32, const float* __restrict__ zs32,
    const _Float16* __restrict__ wfh, const _Float16* __restrict__ wsh,
    const float* __restrict__ bhhF, const float* __restrict__ bhhS,
    const float* __restrict__ giF, const float* __restrict__ giS,
    float* __restrict__ hfn32, _Float16* __restrict__ hfnh,
    float* __restrict__ hsn32, _Float16* __restrict__ hsnh)
{
    const int slow = blockIdx.z;
    const _Float16* Ah = slow ? zsh : zfh;
    const float* H  = slow ? zs32 : zf32;
    const _Float16* Wh = slow ? wsh : wfh;
    const float* bhh = slow ? bhhS : bhhF;
    const float* gi  = slow ? giS  : giF;
    float* hn32 = slow ? hsn32 : hfn32;
    _Float16* hnh = slow ? hsnh : hfnh;

    const int tid = threadIdx.x;
    const int l  = tid & 63;
    const int wv = tid >> 6;
    const int wr = wv >> 1, wc = wv & 1;
    const int row0 = blockIdx.y * 64 + wr * 32;
    const int col0 = blockIdx.x * 64 + wc * 32;
    const int lr = l & 15;
    const int koff = (l >> 4) * 8;

    const half8v* pa[2];
    pa[0] = (const half8v*)(Ah + (size_t)(row0 + lr) * DD + koff);
    pa[1] = (const half8v*)(Ah + (size_t)(row0 + 16 + lr) * DD + koff);
    const half8v* pb[3][2];
    #pragma unroll
    for (int g = 0; g < 3; ++g)
        #pragma unroll
        for (int ni = 0; ni < 2; ++ni)
            pb[g][ni] = (const half8v*)(Wh + (size_t)(g * 512 + col0 + ni * 16 + lr) * DD + koff);

    f32x4 acc[3][2][2];
    #pragma unroll
    for (int g = 0; g < 3; ++g)
        #pragma unroll
        for (int mi = 0; mi < 2; ++mi)
            #pragma unroll
            for (int ni = 0; ni < 2; ++ni)
                acc[g][mi][ni] = (f32x4){0.f, 0.f, 0.f, 0.f};

    // K = 512, 32 per MFMA -> 16 k-steps. Stride per k-step: 32 elems = 4 half8v.
    #pragma unroll
    for (int kt = 0; kt < 16; ++kt) {
        half8v a0 = pa[0][kt * 4];
        half8v a1 = pa[1][kt * 4];
        #pragma unroll
        for (int g = 0; g < 3; ++g) {
            half8v b0 = pb[g][0][kt * 4];
            half8v b1 = pb[g][1][kt * 4];
            acc[g][0][0] = __builtin_amdgcn_mfma_f32_16x16x32_f16(a0, b0, acc[g][0][0], 0, 0, 0);
            acc[g][0][1] = __builtin_amdgcn_mfma_f32_16x16x32_f16(a0, b1, acc[g][0][1], 0, 0, 0);
            acc[g][1][0] = __builtin_amdgcn_mfma_f32_16x16x32_f16(a1, b0, acc[g][1][0], 0, 0, 0);
            acc[g][1][1] = __builtin_amdgcn_mfma_f32_16x16x32_f16(a1, b1, acc[g][1][1], 0, 0, 0);
        }
    }

    // Epilogue: D elem e -> row = base + 4*(l>>4)+e, col = base + (l&15)  [m89-verified]
    const int er4 = (l >> 4) * 4;
    #pragma unroll
    for (int ni = 0; ni < 2; ++ni) {
        const int col = col0 + ni * 16 + lr;
        const float gir = gi[col]       + bhh[col];
        const float giz = gi[col + 512] + bhh[col + 512];
        const float gin = gi[col + 1024];
        const float bn  = bhh[col + 1024];
        #pragma unroll
        for (int mi = 0; mi < 2; ++mi) {
            #pragma unroll
            for (int e = 0; e < 4; ++e) {
                const int row = row0 + mi * 16 + er4 + e;
                float r  = sigm(gir + acc[0][mi][ni][e]);
                float zg = sigm(giz + acc[1][mi][ni][e]);
                float nn = tanhf(gin + r * (acc[2][mi][ni][e] + bn));
                float hv = H[(size_t)row * DD + col];
                float o  = (1.f - zg) * nn + zg * hv;
                hn32[(size_t)row * DD + col] = o;
                hnh [(size_t)row * DD + col] = (_Float16)o;
            }
        }
    }
}

// Gate logits via MFMA: glog = concat(zfn, zs) @ gate_w.T + gate_b (K=1024).
__global__ __launch_bounds__(256) void msd_gate_mfma(
    const _Float16* __restrict__ zfnh, const _Float16* __restrict__ zsh,
    const _Float16* __restrict__ gwh, const float* __restrict__ gb,
    float* __restrict__ glog)
{
    const int tid = threadIdx.x;
    const int l  = tid & 63;
    const int wv = tid >> 6;
    const int wr = wv >> 1, wc = wv & 1;
    const int row0 = blockIdx.y * 64 + wr * 32;
    const int col0 = blockIdx.x * 64 + wc * 32;
    const int lr = l & 15;
    const int koff = (l >> 4) * 8;

    const half8v* paf[2];
    paf[0] = (const half8v*)(zfnh + (size_t)(row0 + lr) * DD + koff);
    paf[1] = (const half8v*)(zfnh + (size_t)(row0 + 16 + lr) * DD + koff);
    const half8v* pas[2];
    pas[0] = (const half8v*)(zsh + (size_t)(row0 + lr) * DD + koff);
    pas[1] = (const half8v*)(zsh + (size_t)(row0 + 16 + lr) * DD + koff);
    const half8v* pbp[2];
    pbp[0] = (const half8v*)(gwh + (size_t)(col0 + lr) * 1024 + koff);
    pbp[1] = (const half8v*)(gwh + (size_t)(col0 + 16 + lr) * 1024 + koff);

    f32x4 acc[2][2];
    #pragma unroll
    for (int mi = 0; mi < 2; ++mi)
        #pragma unroll
        for (int ni = 0; ni < 2; ++ni)
            acc[mi][ni] = (f32x4){0.f, 0.f, 0.f, 0.f};

    // K in [0,512): A from zfnh
    #pragma unroll
    for (int kt = 0; kt < 16; ++kt) {
        half8v a0 = paf[0][kt * 4];
        half8v a1 = paf[1][kt * 4];
        half8v b0 = pbp[0][kt * 4];
        half8v b1 = pbp[1][kt * 4];
        acc[0][0] = __builtin_amdgcn_mfma_f32_16x16x32_f16(a0, b0, acc[0][0], 0, 0, 0);
        acc[0][1] = __builtin_amdgcn_mfma_f32_16x16x32_f16(a0, b1, acc[0][1], 0, 0, 0);
        acc[1][0] = __builtin_amdgcn_mfma_f32_16x16x32_f16(a1, b0, acc[1][0], 0, 0, 0);
        acc[1][1] = __builtin_amdgcn_mfma_f32_16x16x32_f16(a1, b1, acc[1][1], 0, 0, 0);
    }
    // K in [512,1024): A from zsh; B k-offset 512 elems = 64 half8v
    #pragma unroll
    for (int kt = 0; kt < 16; ++kt) {
        half8v a0 = pas[0][kt * 4];
        half8v a1 = pas[1][kt * 4];
        half8v b0 = pbp[0][64 + kt * 4];
        half8v b1 = pbp[1][64 + kt * 4];
        acc[0][0] = __builtin_amdgcn_mfma_f32_16x16x32_f16(a0, b0, acc[0][0], 0, 0, 0);
        acc[0][1] = __builtin_amdgcn_mfma_f32_16x16x32_f16(a0, b1, acc[0][1], 0, 0, 0);
        acc[1][0] = __builtin_amdgcn_mfma_f32_16x16x32_f16(a1, b0, acc[1][0], 0, 0, 0);
        acc[1][1] = __builtin_amdgcn_mfma_f32_16x16x32_f16(a1, b1, acc[1][1], 0, 0, 0);
    }

    const int er4 = (l >> 4) * 4;
    #pragma unroll
    for (int ni = 0; ni < 2; ++ni) {
        const int col = col0 + ni * 16 + lr;
        const float bias = gb[col];
        #pragma unroll
        for (int mi = 0; mi < 2; ++mi) {
            #pragma unroll
            for (int e = 0; e < 4; ++e) {
                const int row = row0 + mi * 16 + er4 + e;
                glog[(size_t)row * DD + col] = acc[mi][ni][e] + bias;
            }
        }
    }
}

// Fuse: g = sigmoid(glog); pre = g*zfn + (1-g)*zs + zf_old; out = LN(pre).
// Writes fp32 carry AND fp16 shadow (next step's fast-GRU A operand).
__global__ __launch_bounds__(128) void msd_fuse_ln_kernel(
    const float* __restrict__ glog, const float* __restrict__ zfn,
    const float* __restrict__ zs, const float* __restrict__ zfold,
    const float* __restrict__ gamma, const float* __restrict__ beta,
    float* __restrict__ outt, float* __restrict__ zfnext,
    _Float16* __restrict__ zfnexth, int TD)
{
    int b = blockIdx.x;
    int j = threadIdx.x * 4;
    size_t base = (size_t)b * DD + j;
    float4 gl = *reinterpret_cast<const float4*>(glog + base);
    float4 fa = *reinterpret_cast<const float4*>(zfn + base);
    float4 sa = *reinterpret_cast<const float4*>(zs + base);
    float4 fo = *reinterpret_cast<const float4*>(zfold + base);

    float p[4];
    {
        float g0 = sigm(gl.x); p[0] = g0 * fa.x + (1.f - g0) * sa.x + fo.x;
        float g1 = sigm(gl.y); p[1] = g1 * fa.y + (1.f - g1) * sa.y + fo.y;
        float g2 = sigm(gl.z); p[2] = g2 * fa.z + (1.f - g2) * sa.z + fo.z;
        float g3 = sigm(gl.w); p[3] = g3 * fa.w + (1.f - g3) * sa.w + fo.w;
    }
    float s  = p[0] + p[1] + p[2] + p[3];
    float s2 = p[0] * p[0] + p[1] * p[1] + p[2] * p[2] + p[3] * p[3];
    #pragma unroll
    for (int off = 32; off > 0; off >>= 1) {
        s  += __shfl_down(s, off);
        s2 += __shfl_down(s2, off);
    }
    __shared__ float red[4];
    if ((threadIdx.x & 63) == 0) { int w = threadIdx.x >> 6; red[w] = s; red[2 + w] = s2; }
    __syncthreads();
    float S  = red[0] + red[1];
    float S2 = red[2] + red[3];
    float mu  = S * (1.0f / DD);
    float var = S2 * (1.0f / DD) - mu * mu;
    float inv = rsqrtf(var + 1e-5f);
    float4 gm = *reinterpret_cast<const float4*>(gamma + j);
    float4 bt = *reinterpret_cast<const float4*>(beta + j);
    float4 o;
    o.x = (p[0] - mu) * inv * gm.x + bt.x;
    o.y = (p[1] - mu) * inv * gm.y + bt.y;
    o.z = (p[2] - mu) * inv * gm.z + bt.z;
    o.w = (p[3] - mu) * inv * gm.w + bt.w;
    *reinterpret_cast<float4*>(outt + (size_t)b * TD + j) = o;
    *reinterpret_cast<float4*>(zfnext + base) = o;
    _Float16 oh[4] = {(_Float16)o.x, (_Float16)o.y, (_Float16)o.z, (_Float16)o.w};
    *reinterpret_cast<ushort4*>(zfnexth + base) = *reinterpret_cast<ushort4*>(oh);
}

extern "C" void kernel_launch(void* const* d_in, const int* in_sizes, int n_in,
                              void* d_out, int out_size, void* d_ws, size_t ws_size,
                              hipStream_t stream)
{
    const float* z_init = (const float*)d_in[0];
    const float* emb    = (const float*)d_in[1];
    const float* f_wih  = (const float*)d_in[2];
    const float* f_whh  = (const float*)d_in[3];
    const float* f_bih  = (const float*)d_in[4];
    const float* f_bhh  = (const float*)d_in[5];
    const float* s_wih  = (const float*)d_in[6];
    const float* s_whh  = (const float*)d_in[7];
    const float* s_bih  = (const float*)d_in[8];
    const float* s_bhh  = (const float*)d_in[9];
    const float* gw     = (const float*)d_in[10];
    const float* gb     = (const float*)d_in[11];
    const float* gamma  = (const float*)d_in[12];
    const float* beta   = (const float*)d_in[13];

    const int B = in_sizes[0] / DD;          // 2048
    const int T = out_size / in_sizes[0];    // 64
    float* out = (float*)d_out;

    char* p = (char*)d_ws;
    auto alloc = [&](size_t bytes) { char* q = p; p += (bytes + 255) & ~(size_t)255; return q; };

    float* gi_f = (float*)alloc((size_t)T * G3 * 4);
    float* gi_s = (float*)alloc((size_t)T * G3 * 4);
    _Float16* wfh = (_Float16*)alloc((size_t)G3 * DD * 2);
    _Float16* wsh = (_Float16*)alloc((size_t)G3 * DD * 2);
    _Float16* gwh = (_Float16*)alloc((size_t)DD * 1024 * 2);
    size_t bd4 = (size_t)B * DD * 4;
    size_t bd2 = (size_t)B * DD * 2;
    float* zf0  = (float*)alloc(bd4);
    float* zf1  = (float*)alloc(bd4);
    float* zs0  = (float*)alloc(bd4);
    float* zs1  = (float*)alloc(bd4);
    float* zfn32 = (float*)alloc(bd4);
    float* glog  = (float*)alloc(bd4);
    _Float16* zfh   = (_Float16*)alloc(bd2);
    _Float16* zsh0  = (_Float16*)alloc(bd2);
    _Float16* zsh1  = (_Float16*)alloc(bd2);
    _Float16* zfnh  = (_Float16*)alloc(bd2);

    msd_gi_kernel<<<dim3(T, 12), 256, 0, stream>>>(emb, f_wih, f_bih, s_wih, s_bih, gi_f, gi_s);
    msd_f2h_kernel<<<(G3 * DD / 4 + 255) / 256, 256, 0, stream>>>(f_whh, wfh, G3 * DD / 4);
    msd_f2h_kernel<<<(G3 * DD / 4 + 255) / 256, 256, 0, stream>>>(s_whh, wsh, G3 * DD / 4);
    msd_f2h_kernel<<<(DD * 1024 / 4 + 255) / 256, 256, 0, stream>>>(gw, gwh, DD * 1024 / 4);
    msd_init_kernel<<<(B * DD + 255) / 256, 256, 0, stream>>>(z_init, zf0, zs0, zfh, zsh0, B * DD);

    float* zfc[2] = {zf0, zf1};
    float* zsc[2] = {zs0, zs1};
    _Float16* zshc[2] = {zsh0, zsh1};
    int fc = 0, sc = 0;
    for (int t = 0; t < T; ++t) {
        int upd = (t % 2 == 0) ? 1 : 0;
        dim3 grid(DD / 64, B / 64, 1 + upd);
        msd_gru_mfma<<<grid, 256, 0, stream>>>(
            zfh, zshc[sc], zfc[fc], zsc[sc], wfh, wsh, f_bhh, s_bhh,
            gi_f + (size_t)t * G3, gi_s + (size_t)t * G3,
            zfn32, zfnh, zsc[sc ^ 1], zshc[sc ^ 1]);
        if (upd) sc ^= 1;
        msd_gate_mfma<<<dim3(DD / 64, B / 64), 256, 0, stream>>>(zfnh, zshc[sc], gwh, gb, glog);
        msd_fuse_ln_kernel<<<B, 128, 0, stream>>>(glog, zfn32, zsc[sc], zfc[fc], gamma, beta,
            out + (size_t)t * DD, zfc[fc ^ 1], zfh, T * DD);
        fc ^= 1;
    }
}